// Round 1
// baseline (1606.109 us; speedup 1.0000x reference)
//
#include <hip/hip_runtime.h>

// SelfAttention: out = softmax(causal((Ez Wq^T)(Ez Wk^T)^T / sqrt(512))) (Ez Wv^T)
// B=32, L=2048, DIM=512. f32 in/out; bf16 MFMA internally (threshold 4.375e-2).
// ws layout: Qb[32*2048*512] bf16, Kb[...] bf16, Vtb (transposed [b][e][l]) bf16.

typedef __attribute__((ext_vector_type(8))) short short8;
typedef __attribute__((ext_vector_type(4))) float f32x4;

#define DIM 512
#define LSEQ 2048
#define NB 32

__device__ __forceinline__ short f2b(float f) {
  unsigned u = __builtin_bit_cast(unsigned, f);
  return (short)((u + 0x7fffu + ((u >> 16) & 1u)) >> 16);  // RNE f32->bf16
}

// ---------------- projection GEMM: C[m][n] = sum_d Ez[m][d] * W[n][d] --------
// g=0 -> Qb row-major, g=1 -> Kb row-major, g=2 -> Vtb transposed [b][e][l].
__global__ __launch_bounds__(256) void proj_kernel(
    const float* __restrict__ Ez, const float* __restrict__ Wq,
    const float* __restrict__ Wk, const float* __restrict__ Wv,
    const int* __restrict__ zp,
    short* __restrict__ Qb, short* __restrict__ Kb, short* __restrict__ Vtb) {
  int g = blockIdx.z;
  int z = *zp;
  const float* W = (g == 0 ? Wq : (g == 1 ? Wk : Wv)) + (size_t)z * DIM * DIM;
  __shared__ short As[64][40];  // +8 bf16 pad: breaks power-of-2 row stride
  __shared__ short Bs[64][40];
  int tid = threadIdx.x, lane = tid & 63, wid = tid >> 6;
  int l15 = lane & 15, lg = lane >> 4;
  int m0 = blockIdx.y * 64, n0 = blockIdx.x * 64;
  int wr = wid >> 1, wc = wid & 1;
  int srow = tid >> 2, scg = tid & 3;
  f32x4 zero4 = {0.f, 0.f, 0.f, 0.f};
  f32x4 acc[2][2] = {{zero4, zero4}, {zero4, zero4}};
  for (int kt = 0; kt < 16; kt++) {
    const float* asrc = Ez + (size_t)(m0 + srow) * DIM + kt * 32 + scg * 8;
    const float* bsrc = W + (size_t)(n0 + srow) * DIM + kt * 32 + scg * 8;
    float4 a0 = *(const float4*)asrc, a1 = *(const float4*)(asrc + 4);
    float4 b0 = *(const float4*)bsrc, b1 = *(const float4*)(bsrc + 4);
    short8 av, bv;
    av[0]=f2b(a0.x); av[1]=f2b(a0.y); av[2]=f2b(a0.z); av[3]=f2b(a0.w);
    av[4]=f2b(a1.x); av[5]=f2b(a1.y); av[6]=f2b(a1.z); av[7]=f2b(a1.w);
    bv[0]=f2b(b0.x); bv[1]=f2b(b0.y); bv[2]=f2b(b0.z); bv[3]=f2b(b0.w);
    bv[4]=f2b(b1.x); bv[5]=f2b(b1.y); bv[6]=f2b(b1.z); bv[7]=f2b(b1.w);
    *(short8*)&As[srow][scg * 8] = av;
    *(short8*)&Bs[srow][scg * 8] = bv;
    __syncthreads();
    short8 af[2], bfr[2];
    #pragma unroll
    for (int m = 0; m < 2; m++)
      af[m] = *(const short8*)&As[wr * 32 + m * 16 + l15][lg * 8];
    #pragma unroll
    for (int n = 0; n < 2; n++)
      bfr[n] = *(const short8*)&Bs[wc * 32 + n * 16 + l15][lg * 8];
    #pragma unroll
    for (int m = 0; m < 2; m++)
      #pragma unroll
      for (int n = 0; n < 2; n++)
        acc[m][n] = __builtin_amdgcn_mfma_f32_16x16x32_bf16(af[m], bfr[n], acc[m][n], 0, 0, 0);
    __syncthreads();
  }
  #pragma unroll
  for (int m = 0; m < 2; m++)
    #pragma unroll
    for (int n = 0; n < 2; n++)
      #pragma unroll
      for (int r = 0; r < 4; r++) {
        int gm = m0 + wr * 32 + m * 16 + lg * 4 + r;   // C/D: row=(lane>>4)*4+reg
        int gn = n0 + wc * 32 + n * 16 + l15;          //       col=lane&15
        short val = f2b(acc[m][n][r]);
        if (g == 0) Qb[(size_t)gm * DIM + gn] = val;
        else if (g == 1) Kb[(size_t)gm * DIM + gn] = val;
        else {
          int b = gm >> 11, l = gm & (LSEQ - 1);
          Vtb[((size_t)b * DIM + gn) * LSEQ + l] = val;  // V transposed
        }
      }
}

// ---------------- flash attention (causal) ----------------
// Block: 64 q-rows of one batch, 4 waves x 16 rows. KV tiles of 32.
__global__ __launch_bounds__(256) void attn_kernel(
    const short* __restrict__ Qb, const short* __restrict__ Kb,
    const short* __restrict__ Vtb, float* __restrict__ out) {
  __shared__ short smem[20480];            // union: K[32][520] (33KB) / Vt[512][40] (40KB)
  __shared__ short P_lds[4][16][40];       // per-wave P transpose buffer
  short (*Kl)[520] = (short(*)[520])smem;
  short (*Vl)[40] = (short(*)[40])smem;
  int tid = threadIdx.x, lane = tid & 63, wid = tid >> 6;
  int l15 = lane & 15, lg = lane >> 4;
  int qb0 = blockIdx.x * 64;
  int batch = blockIdx.y;
  int q0w = qb0 + wid * 16;
  const float SCALE = 0.04419417382415922f;  // 1/sqrt(512)

  // Q fragments in registers: A[i=l15][k], 16 k-tiles of 32
  short8 qf[16];
  const short* qrow = Qb + (size_t)(batch * LSEQ + q0w + l15) * DIM;
  #pragma unroll
  for (int kt = 0; kt < 16; kt++) qf[kt] = *(const short8*)(qrow + kt * 32 + lg * 8);

  f32x4 zero4 = {0.f, 0.f, 0.f, 0.f};
  f32x4 oacc[32];
  #pragma unroll
  for (int i = 0; i < 32; i++) oacc[i] = zero4;
  float mrun[4], lrun[4];
  #pragma unroll
  for (int r = 0; r < 4; r++) { mrun[r] = -1e30f; lrun[r] = 0.f; }

  int nt = qb0 / 32 + 2;  // cover kv <= qb0+63
  for (int t = 0; t < nt; t++) {
    __syncthreads();  // prev PV done reading Vl before K staging overwrites
    {
      int row = tid >> 3, cg = tid & 7;
      const short* src = Kb + (size_t)(batch * LSEQ + t * 32 + row) * DIM + cg * 64;
      #pragma unroll
      for (int i = 0; i < 8; i++)
        *(short8*)&Kl[row][cg * 64 + i * 8] = *(const short8*)(src + i * 8);
    }
    __syncthreads();
    // S = Q K^T  (16x32 per wave, two 16x16 col-tiles)
    f32x4 sacc[2] = {zero4, zero4};
    #pragma unroll
    for (int kt = 0; kt < 16; kt++) {
      #pragma unroll
      for (int c = 0; c < 2; c++) {
        short8 bk = *(const short8*)&Kl[c * 16 + l15][kt * 32 + lg * 8];
        sacc[c] = __builtin_amdgcn_mfma_f32_16x16x32_bf16(qf[kt], bk, sacc[c], 0, 0, 0);
      }
    }
    // online softmax; rows r live at (lane>>4)*4+r, cols at lane&15
    #pragma unroll
    for (int r = 0; r < 4; r++) {
      int q = q0w + lg * 4 + r;
      float s0 = sacc[0][r] * SCALE;
      float s1 = sacc[1][r] * SCALE;
      if (t * 32 + l15 > q) s0 = -1e30f;
      if (t * 32 + 16 + l15 > q) s1 = -1e30f;
      float mx = fmaxf(s0, s1);
      #pragma unroll
      for (int off = 1; off < 16; off <<= 1) mx = fmaxf(mx, __shfl_xor(mx, off, 64));
      float mn = fmaxf(mrun[r], mx);
      float alpha = __expf(mrun[r] - mn);
      mrun[r] = mn;
      float p0 = __expf(s0 - mn), p1 = __expf(s1 - mn);
      float rs = p0 + p1;
      #pragma unroll
      for (int off = 1; off < 16; off <<= 1) rs += __shfl_xor(rs, off, 64);
      lrun[r] = lrun[r] * alpha + rs;
      #pragma unroll
      for (int et = 0; et < 32; et++) oacc[et][r] *= alpha;
      P_lds[wid][lg * 4 + r][l15] = f2b(p0);
      P_lds[wid][lg * 4 + r][16 + l15] = f2b(p1);
    }
    __syncthreads();  // all waves done reading Kl
    {
      int e = tid * 2;  // stage Vt rows [e][kv0..kv0+31]
      const short* src = Vtb + ((size_t)batch * DIM + e) * LSEQ + t * 32;
      #pragma unroll
      for (int i = 0; i < 4; i++) *(short8*)&Vl[e][i * 8] = *(const short8*)(src + i * 8);
      src += LSEQ;
      #pragma unroll
      for (int i = 0; i < 4; i++) *(short8*)&Vl[e + 1][i * 8] = *(const short8*)(src + i * 8);
    }
    __syncthreads();
    // PV: A = P (16x32, from per-wave LDS transpose), B = V via Vt (contiguous reads)
    short8 pa = *(const short8*)&P_lds[wid][l15][lg * 8];
    #pragma unroll
    for (int et = 0; et < 32; et++) {
      short8 bv = *(const short8*)&Vl[et * 16 + l15][lg * 8];
      oacc[et] = __builtin_amdgcn_mfma_f32_16x16x32_bf16(pa, bv, oacc[et], 0, 0, 0);
    }
  }
  // epilogue: out f32, divide by softmax denom
  #pragma unroll
  for (int et = 0; et < 32; et++) {
    #pragma unroll
    for (int r = 0; r < 4; r++) {
      int q = q0w + lg * 4 + r;
      out[((size_t)(batch * LSEQ + q)) * DIM + et * 16 + l15] = oacc[et][r] / lrun[r];
    }
  }
}

extern "C" void kernel_launch(void* const* d_in, const int* in_sizes, int n_in,
                              void* d_out, int out_size, void* d_ws, size_t ws_size,
                              hipStream_t stream) {
  const float* Ez = (const float*)d_in[0];
  const float* Wq = (const float*)d_in[1];
  const float* Wk = (const float*)d_in[2];
  const float* Wv = (const float*)d_in[3];
  const int* zp = (const int*)d_in[4];
  float* out = (float*)d_out;
  short* Qb = (short*)d_ws;
  short* Kb = Qb + (size_t)NB * LSEQ * DIM;
  short* Vtb = Kb + (size_t)NB * LSEQ * DIM;
  hipLaunchKernelGGL(proj_kernel, dim3(8, 1024, 3), dim3(256), 0, stream,
                     Ez, Wq, Wk, Wv, zp, Qb, Kb, Vtb);
  hipLaunchKernelGGL(attn_kernel, dim3(32, 32), dim3(256), 0, stream,
                     Qb, Kb, Vtb, out);
}

// Round 2
// 1486.229 us; speedup vs baseline: 1.0807x; 1.0807x over previous
//
#include <hip/hip_runtime.h>

// SelfAttention: out = softmax(causal((Ez Wq^T)(Ez Wk^T)^T / sqrt(512))) (Ez Wv^T)
// B=32, L=2048, DIM=512. f32 in/out; bf16 MFMA internally (threshold 4.375e-2).
// ws layout: Qb[32*2048*512] bf16, Kb[...] bf16, Vtb (transposed [b][e][l]) bf16.

typedef __attribute__((ext_vector_type(8))) short short8;
typedef __attribute__((ext_vector_type(4))) float f32x4;

#define DIM 512
#define LSEQ 2048
#define NB 32

__device__ __forceinline__ short f2b(float f) {
  unsigned u = __builtin_bit_cast(unsigned, f);
  return (short)((u + 0x7fffu + ((u >> 16) & 1u)) >> 16);  // RNE f32->bf16
}

// ---------------- projection GEMM: C[m][n] = sum_d Ez[m][d] * W[n][d] --------
// g=0 -> Qb row-major, g=1 -> Kb row-major, g=2 -> Vtb transposed [b][e][l].
__global__ __launch_bounds__(256) void proj_kernel(
    const float* __restrict__ Ez, const float* __restrict__ Wq,
    const float* __restrict__ Wk, const float* __restrict__ Wv,
    const int* __restrict__ zp,
    short* __restrict__ Qb, short* __restrict__ Kb, short* __restrict__ Vtb) {
  int g = blockIdx.z;
  int z = *zp;
  const float* W = (g == 0 ? Wq : (g == 1 ? Wk : Wv)) + (size_t)z * DIM * DIM;
  __shared__ short As[64][40];  // +8 bf16 pad: breaks power-of-2 row stride
  __shared__ short Bs[64][40];
  int tid = threadIdx.x, lane = tid & 63, wid = tid >> 6;
  int l15 = lane & 15, lg = lane >> 4;
  int m0 = blockIdx.y * 64, n0 = blockIdx.x * 64;
  int wr = wid >> 1, wc = wid & 1;
  int srow = tid >> 2, scg = tid & 3;
  f32x4 zero4 = {0.f, 0.f, 0.f, 0.f};
  f32x4 acc[2][2] = {{zero4, zero4}, {zero4, zero4}};
  for (int kt = 0; kt < 16; kt++) {
    const float* asrc = Ez + (size_t)(m0 + srow) * DIM + kt * 32 + scg * 8;
    const float* bsrc = W + (size_t)(n0 + srow) * DIM + kt * 32 + scg * 8;
    float4 a0 = *(const float4*)asrc, a1 = *(const float4*)(asrc + 4);
    float4 b0 = *(const float4*)bsrc, b1 = *(const float4*)(bsrc + 4);
    short8 av, bv;
    av[0]=f2b(a0.x); av[1]=f2b(a0.y); av[2]=f2b(a0.z); av[3]=f2b(a0.w);
    av[4]=f2b(a1.x); av[5]=f2b(a1.y); av[6]=f2b(a1.z); av[7]=f2b(a1.w);
    bv[0]=f2b(b0.x); bv[1]=f2b(b0.y); bv[2]=f2b(b0.z); bv[3]=f2b(b0.w);
    bv[4]=f2b(b1.x); bv[5]=f2b(b1.y); bv[6]=f2b(b1.z); bv[7]=f2b(b1.w);
    *(short8*)&As[srow][scg * 8] = av;
    *(short8*)&Bs[srow][scg * 8] = bv;
    __syncthreads();
    short8 af[2], bfr[2];
    #pragma unroll
    for (int m = 0; m < 2; m++)
      af[m] = *(const short8*)&As[wr * 32 + m * 16 + l15][lg * 8];
    #pragma unroll
    for (int n = 0; n < 2; n++)
      bfr[n] = *(const short8*)&Bs[wc * 32 + n * 16 + l15][lg * 8];
    #pragma unroll
    for (int m = 0; m < 2; m++)
      #pragma unroll
      for (int n = 0; n < 2; n++)
        acc[m][n] = __builtin_amdgcn_mfma_f32_16x16x32_bf16(af[m], bfr[n], acc[m][n], 0, 0, 0);
    __syncthreads();
  }
  #pragma unroll
  for (int m = 0; m < 2; m++)
    #pragma unroll
    for (int n = 0; n < 2; n++)
      #pragma unroll
      for (int r = 0; r < 4; r++) {
        int gm = m0 + wr * 32 + m * 16 + lg * 4 + r;   // C/D: row=(lane>>4)*4+reg
        int gn = n0 + wc * 32 + n * 16 + l15;          //       col=lane&15
        short val = f2b(acc[m][n][r]);
        if (g == 0) Qb[(size_t)gm * DIM + gn] = val;
        else if (g == 1) Kb[(size_t)gm * DIM + gn] = val;
        else {
          int b = gm >> 11, l = gm & (LSEQ - 1);
          Vtb[((size_t)b * DIM + gn) * LSEQ + l] = val;  // V transposed
        }
      }
}

// ---------------- flash attention (causal) ----------------
// Block: 4 waves x 16 q-rows = 64 q-rows; processes TWO q-tiles (i, 31-i) for
// uniform work (66 KV-tiles per block). KV tiles of 32.
// K LDS [32][512] chunk-swizzled (chunk ^= row&7), V LDS [512][32] chunk-
// swizzled (chunk ^= (row>>1)&3); both conflict-free for ds_read_b128.
__global__ __launch_bounds__(256) void attn_kernel(
    const short* __restrict__ Qb, const short* __restrict__ Kb,
    const short* __restrict__ Vtb, float* __restrict__ out) {
  __shared__ short Kl[32 * 512];      // 32 KB
  __shared__ short Vl[512 * 32];      // 32 KB
  __shared__ short P_lds[4][16][36];  // per-wave P transpose, 4.5 KB
  int tid = threadIdx.x, lane = tid & 63, wid = tid >> 6;
  int l15 = lane & 15, lg = lane >> 4;
  int batch = blockIdx.y;
  const float SCALE = 0.04419417382415922f;  // 1/sqrt(512)

  for (int qpass = 0; qpass < 2; qpass++) {
    int qt = (qpass == 0) ? (int)blockIdx.x : (31 - (int)blockIdx.x);
    int qb0 = qt * 64;
    int q0w = qb0 + wid * 16;

    // Q fragments in registers: A[row=l15][k], 16 k-tiles of 32
    short8 qf[16];
    const short* qrow = Qb + (size_t)(batch * LSEQ + q0w + l15) * DIM;
    #pragma unroll
    for (int kt = 0; kt < 16; kt++) qf[kt] = *(const short8*)(qrow + kt * 32 + lg * 8);

    f32x4 zero4 = {0.f, 0.f, 0.f, 0.f};
    f32x4 oacc[32];
    #pragma unroll
    for (int i = 0; i < 32; i++) oacc[i] = zero4;
    float mrun[4], lrun[4];
    #pragma unroll
    for (int r = 0; r < 4; r++) { mrun[r] = -1e30f; lrun[r] = 0.f; }

    int nt = qb0 / 32 + 2;  // cover kv <= qb0+63
    for (int t = 0; t < nt; t++) {
      __syncthreads();  // prev tile's K/V reads done before restaging
      {  // stage K rows [t*32 .. t*32+31], swizzled; coalesced 128B runs
        int r = tid >> 3, cg = tid & 7;
        const short* src = Kb + (size_t)(batch * LSEQ + t * 32 + r) * DIM;
        short* dst = &Kl[r * 512];
        int sw = r & 7;
        #pragma unroll
        for (int i = 0; i < 8; i++) {
          int j = i * 8 + cg;
          *(short8*)(dst + ((j ^ sw) * 8)) = *(const short8*)(src + j * 8);
        }
      }
      {  // stage V^T rows e=tid, tid+256 (cols t*32..+31), swizzled
        #pragma unroll
        for (int h = 0; h < 2; h++) {
          int e = tid + h * 256;
          const short* src = Vtb + ((size_t)batch * DIM + e) * LSEQ + t * 32;
          short* dst = &Vl[e * 32];
          int sw = (e >> 1) & 3;
          #pragma unroll
          for (int c = 0; c < 4; c++)
            *(short8*)(dst + ((c ^ sw) * 8)) = *(const short8*)(src + c * 8);
        }
      }
      __syncthreads();
      if (t * 32 <= q0w + 15) {  // wave-local skip of fully-masked tiles
        // S = Q K^T  (16x32 per wave, two 16x16 col-tiles)
        f32x4 sacc[2] = {zero4, zero4};
        #pragma unroll
        for (int kt = 0; kt < 16; kt++) {
          #pragma unroll
          for (int c = 0; c < 2; c++) {
            int kr = c * 16 + l15;
            int j = kt * 4 + lg;
            short8 bk = *(const short8*)&Kl[kr * 512 + ((j ^ (kr & 7)) * 8)];
            sacc[c] = __builtin_amdgcn_mfma_f32_16x16x32_bf16(qf[kt], bk, sacc[c], 0, 0, 0);
          }
        }
        // online softmax; rows r at q=(lane>>4)*4+r, cols at lane&15
        #pragma unroll
        for (int r = 0; r < 4; r++) {
          int q = q0w + lg * 4 + r;
          float s0 = sacc[0][r] * SCALE;
          float s1 = sacc[1][r] * SCALE;
          if (t * 32 + l15 > q) s0 = -1e30f;
          if (t * 32 + 16 + l15 > q) s1 = -1e30f;
          float mx = fmaxf(s0, s1);
          #pragma unroll
          for (int off = 1; off < 16; off <<= 1) mx = fmaxf(mx, __shfl_xor(mx, off, 64));
          float mn = fmaxf(mrun[r], mx);
          float alpha = __expf(mrun[r] - mn);
          mrun[r] = mn;
          float p0 = __expf(s0 - mn), p1 = __expf(s1 - mn);
          float rs = p0 + p1;
          #pragma unroll
          for (int off = 1; off < 16; off <<= 1) rs += __shfl_xor(rs, off, 64);
          lrun[r] = lrun[r] * alpha + rs;
          #pragma unroll
          for (int et = 0; et < 32; et++) oacc[et][r] *= alpha;
          P_lds[wid][lg * 4 + r][l15] = f2b(p0);
          P_lds[wid][lg * 4 + r][16 + l15] = f2b(p1);
        }
        // PV: A = P (16x32, per-wave LDS transpose; wave-local so no barrier)
        short8 pa = *(const short8*)&P_lds[wid][l15][lg * 8];
        #pragma unroll
        for (int et = 0; et < 32; et++) {
          int e = et * 16 + l15;
          short8 bv = *(const short8*)&Vl[e * 32 + ((lg ^ ((e >> 1) & 3)) * 8)];
          oacc[et] = __builtin_amdgcn_mfma_f32_16x16x32_bf16(pa, bv, oacc[et], 0, 0, 0);
        }
      }
    }
    // epilogue: out f32, divide by softmax denom
    #pragma unroll
    for (int et = 0; et < 32; et++) {
      #pragma unroll
      for (int r = 0; r < 4; r++) {
        int q = q0w + lg * 4 + r;
        out[((size_t)(batch * LSEQ + q)) * DIM + et * 16 + l15] = oacc[et][r] / lrun[r];
      }
    }
  }
}

extern "C" void kernel_launch(void* const* d_in, const int* in_sizes, int n_in,
                              void* d_out, int out_size, void* d_ws, size_t ws_size,
                              hipStream_t stream) {
  const float* Ez = (const float*)d_in[0];
  const float* Wq = (const float*)d_in[1];
  const float* Wk = (const float*)d_in[2];
  const float* Wv = (const float*)d_in[3];
  const int* zp = (const int*)d_in[4];
  float* out = (float*)d_out;
  short* Qb = (short*)d_ws;
  short* Kb = Qb + (size_t)NB * LSEQ * DIM;
  short* Vtb = Kb + (size_t)NB * LSEQ * DIM;
  hipLaunchKernelGGL(proj_kernel, dim3(8, 1024, 3), dim3(256), 0, stream,
                     Ez, Wq, Wk, Wv, zp, Qb, Kb, Vtb);
  hipLaunchKernelGGL(attn_kernel, dim3(16, 32), dim3(256), 0, stream,
                     Qb, Kb, Vtb, out);
}

// Round 4
// 863.126 us; speedup vs baseline: 1.8608x; 1.7219x over previous
//
#include <hip/hip_runtime.h>
#include <hip/hip_bf16.h>

// SelfAttention: out = softmax(causal((Ez Wq^T)(Ez Wk^T)^T / sqrt(512))) (Ez Wv^T)
// B=32, L=2048, DIM=512. f32 in/out; bf16 MFMA internally.
// ws: Qb (bf16, Q*SCALE pre-folded), Kb (bf16), Vtb (bf16, transposed [b][e][l]).

typedef __attribute__((ext_vector_type(8))) short short8;
typedef __attribute__((ext_vector_type(4))) short short4v;
typedef __attribute__((ext_vector_type(4))) float f32x4;

#define DIM 512
#define LSEQ 2048
#define NB 32
#define SCALE 0.04419417382415922f       // 1/sqrt(512), folded into Qb at proj
#define LOG2E 1.4426950408889634f        // scores -> exp2 domain (SCALE NOT re-applied)

__device__ __forceinline__ short f2bs(float f) {
  __hip_bfloat16 h = __float2bfloat16(f);
  return __builtin_bit_cast(short, h);
}

__device__ __forceinline__ void gld16(const void* g, void* l) {
  __builtin_amdgcn_global_load_lds(
      (const unsigned int __attribute__((address_space(1)))*)g,
      (unsigned int __attribute__((address_space(3)))*)l, 16, 0, 0);
}

// ---------------- projection GEMM: C[m][n] = sum_d Ez[m][d] * W[n][d] --------
// BM=128, BN=512 (full N per block -> Ez read once per g), BK=32, 8 waves.
__global__ __launch_bounds__(512, 2) void proj_kernel(
    const float* __restrict__ Ez, const float* __restrict__ Wq,
    const float* __restrict__ Wk, const float* __restrict__ Wv,
    const int* __restrict__ zp,
    short* __restrict__ Qb, short* __restrict__ Kb, short* __restrict__ Vtb) {
  int g = blockIdx.z;
  int z = *zp;
  const float* W = (g == 0 ? Wq : (g == 1 ? Wk : Wv)) + (size_t)z * DIM * DIM;
  __shared__ short As[128][40];  // +8 pad -> 2-way (free) on frag reads
  __shared__ short Bs[512][40];
  int tid = threadIdx.x, lane = tid & 63, wid = tid >> 6;
  int l15 = lane & 15, lg = lane >> 4;
  int m0 = blockIdx.x * 128;
  f32x4 zero4 = {0.f, 0.f, 0.f, 0.f};
  f32x4 acc[32];
  #pragma unroll
  for (int i = 0; i < 32; i++) acc[i] = zero4;
  int arow = tid >> 2, acg = tid & 3;
  #pragma unroll 1
  for (int kt = 0; kt < 16; kt++) {
    const float* asrc = Ez + (size_t)(m0 + arow) * DIM + kt * 32 + acg * 8;
    float4 a0 = *(const float4*)asrc, a1 = *(const float4*)(asrc + 4);
    float4 b0[4], b1[4];
    #pragma unroll
    for (int ii = 0; ii < 4; ii++) {
      const float* bsrc = W + (size_t)(arow + ii * 128) * DIM + kt * 32 + acg * 8;
      b0[ii] = *(const float4*)bsrc;
      b1[ii] = *(const float4*)(bsrc + 4);
    }
    __syncthreads();  // prev step's frag reads done
    {
      short8 av;
      av[0]=f2bs(a0.x); av[1]=f2bs(a0.y); av[2]=f2bs(a0.z); av[3]=f2bs(a0.w);
      av[4]=f2bs(a1.x); av[5]=f2bs(a1.y); av[6]=f2bs(a1.z); av[7]=f2bs(a1.w);
      *(short8*)&As[arow][acg * 8] = av;
    }
    #pragma unroll
    for (int ii = 0; ii < 4; ii++) {
      short8 bv;
      bv[0]=f2bs(b0[ii].x); bv[1]=f2bs(b0[ii].y); bv[2]=f2bs(b0[ii].z); bv[3]=f2bs(b0[ii].w);
      bv[4]=f2bs(b1[ii].x); bv[5]=f2bs(b1[ii].y); bv[6]=f2bs(b1[ii].z); bv[7]=f2bs(b1[ii].w);
      *(short8*)&Bs[arow + ii * 128][acg * 8] = bv;
    }
    __syncthreads();
    short8 af = *(const short8*)&As[wid * 16 + l15][lg * 8];
    #pragma unroll
    for (int et = 0; et < 32; et++) {
      short8 bf = *(const short8*)&Bs[et * 16 + l15][lg * 8];
      acc[et] = __builtin_amdgcn_mfma_f32_16x16x32_bf16(af, bf, acc[et], 0, 0, 0);
    }
  }
  // epilogue: C/D layout row=(lane>>4)*4+reg, col=lane&15
  int gm0 = m0 + wid * 16 + lg * 4;
  if (g == 2) {
    int b = gm0 >> 11, l0 = gm0 & (LSEQ - 1);  // 4-row group within one batch
    #pragma unroll
    for (int et = 0; et < 32; et++) {
      short4v v;
      v[0]=f2bs(acc[et][0]); v[1]=f2bs(acc[et][1]); v[2]=f2bs(acc[et][2]); v[3]=f2bs(acc[et][3]);
      *(short4v*)&Vtb[((size_t)b * DIM + et * 16 + l15) * LSEQ + l0] = v;
    }
  } else {
    short* dst = (g == 0 ? Qb : Kb);
    float sc = (g == 0 ? SCALE : 1.0f);  // fold 1/sqrt(512) into Q
    #pragma unroll
    for (int et = 0; et < 32; et++)
      #pragma unroll
      for (int r = 0; r < 4; r++)
        dst[(size_t)(gm0 + r) * DIM + et * 16 + l15] = f2bs(acc[et][r] * sc);
  }
}

// ---------------- flash attention (causal) ----------------
// 512 threads, 8 waves x 16 q-rows = 128-row Q tile; two tiles (i, 15-i) per
// block -> uniform 68 KV-tiles. KVBLK=32, K+V double-buffered, staged via
// global_load_lds (linear LDS dest, pre-swizzled GLOBAL source), 1 barrier/tile.
__device__ __forceinline__ void stage_kv(const short* __restrict__ Kb,
                                         const short* __restrict__ Vtb,
                                         short* Klbuf, short* Vlbuf,
                                         int batch, int t, int wid, int lane) {
  #pragma unroll
  for (int ii = 0; ii < 4; ii++) {          // K: rows wid, wid+8, wid+16, wid+24
    int r = wid + ii * 8;                   // r&7 == wid
    const short* src = Kb + (size_t)(batch * LSEQ + t * 32 + r) * DIM + ((lane ^ wid) * 8);
    gld16(src, Klbuf + r * 512);            // wave-uniform LDS base + lane*16
  }
  #pragma unroll
  for (int ii = 0; ii < 4; ii++) {          // V: 16 e-rows per instruction
    int e0 = (wid * 4 + ii) * 16;
    int e = e0 + (lane >> 2);
    int c = lane & 3;
    const short* src = Vtb + ((size_t)(batch * DIM + e)) * LSEQ + t * 32 + (((c ^ ((e >> 1) & 3))) * 8);
    gld16(src, Vlbuf + e0 * 32);
  }
}

__global__ __launch_bounds__(512, 2) void attn_kernel(
    const short* __restrict__ Qb, const short* __restrict__ Kb,
    const short* __restrict__ Vtb, float* __restrict__ out) {
  __shared__ short Kl[2][32 * 512];   // 64 KB dbuf
  __shared__ short Vl[2][512 * 32];   // 64 KB dbuf
  __shared__ short P_lds[8][16][36];  // per-wave P transpose, 9 KB
  int tid = threadIdx.x, lane = tid & 63, wid = tid >> 6;
  int l15 = lane & 15, lg = lane >> 4;
  int batch = blockIdx.y;
  int sw3 = (l15 >> 1) & 3;  // PV read swizzle (lane-const)
  f32x4 zero4 = {0.f, 0.f, 0.f, 0.f};

  for (int qpass = 0; qpass < 2; qpass++) {
    int qt = qpass ? 15 - (int)blockIdx.x : (int)blockIdx.x;
    int qb0 = qt * 128;
    int q0w = qb0 + wid * 16;
    int nt = qt * 4 + 4;

    stage_kv(Kb, Vtb, Kl[0], Vl[0], batch, 0, wid, lane);  // prologue prefetch

    short8 qf[16];  // Q rows in regs (pre-scaled by 1/sqrt(512) at proj)
    const short* qrow = Qb + (size_t)(batch * LSEQ + q0w + l15) * DIM;
    #pragma unroll
    for (int kt = 0; kt < 16; kt++) qf[kt] = *(const short8*)(qrow + kt * 32 + lg * 8);

    f32x4 oacc[32];
    #pragma unroll
    for (int i = 0; i < 32; i++) oacc[i] = zero4;
    float mrun[4], lrun[4];
    #pragma unroll
    for (int r = 0; r < 4; r++) { mrun[r] = -1e30f; lrun[r] = 0.f; }

    __syncthreads();  // drains prologue stage (vmcnt) + syncs

    for (int t = 0; t < nt; t++) {
      int cur = t & 1;
      if (t + 1 < nt)
        stage_kv(Kb, Vtb, Kl[cur ^ 1], Vl[cur ^ 1], batch, t + 1, wid, lane);  // prefetch

      if (t * 32 <= q0w + 15) {  // wave-local causal skip
        const short* Kc = Kl[cur];
        const short* Vc = Vl[cur];
        f32x4 sacc[2] = {zero4, zero4};
        __builtin_amdgcn_s_setprio(1);
        #pragma unroll
        for (int kt = 0; kt < 16; kt++) {
          #pragma unroll
          for (int c = 0; c < 2; c++) {
            int kr = c * 16 + l15;
            int j = kt * 4 + lg;
            short8 bk = *(const short8*)&Kc[kr * 512 + ((j ^ (kr & 7)) * 8)];
            sacc[c] = __builtin_amdgcn_mfma_f32_16x16x32_bf16(qf[kt], bk, sacc[c], 0, 0, 0);
          }
        }
        __builtin_amdgcn_s_setprio(0);
        // online softmax, exp2 domain; defer-max (THR = 8 nats = 11.5 log2)
        float alpha[4];
        bool need = false;
        #pragma unroll
        for (int r = 0; r < 4; r++) {
          int q = q0w + lg * 4 + r;
          float s0 = sacc[0][r] * LOG2E;   // SCALE already folded into Qb
          float s1 = sacc[1][r] * LOG2E;
          if (t * 32 + l15 > q) s0 = -1e30f;
          if (t * 32 + 16 + l15 > q) s1 = -1e30f;
          float mx = fmaxf(s0, s1);
          #pragma unroll
          for (int off = 1; off < 16; off <<= 1) mx = fmaxf(mx, __shfl_xor(mx, off, 64));
          if (mx > mrun[r] + 11.5f) {
            alpha[r] = exp2f(mrun[r] - mx);
            mrun[r] = mx;
            need = true;
          } else {
            alpha[r] = 1.f;
          }
          float p0 = exp2f(s0 - mrun[r]);
          float p1 = exp2f(s1 - mrun[r]);
          float rs = p0 + p1;
          #pragma unroll
          for (int off = 1; off < 16; off <<= 1) rs += __shfl_xor(rs, off, 64);
          lrun[r] = lrun[r] * alpha[r] + rs;
          P_lds[wid][lg * 4 + r][l15] = f2bs(p0);
          P_lds[wid][lg * 4 + r][16 + l15] = f2bs(p1);
        }
        if (__any(need)) {  // O-rescale only when some row's max grew
          #pragma unroll
          for (int r = 0; r < 4; r++)
            #pragma unroll
            for (int et = 0; et < 32; et++) oacc[et][r] *= alpha[r];
        }
        short8 pa = *(const short8*)&P_lds[wid][l15][lg * 8];  // wave-local RAW
        __builtin_amdgcn_s_setprio(1);
        #pragma unroll
        for (int et = 0; et < 32; et++) {
          short8 bv = *(const short8*)&Vc[(et * 16 + l15) * 32 + ((lg ^ sw3) * 8)];
          oacc[et] = __builtin_amdgcn_mfma_f32_16x16x32_bf16(pa, bv, oacc[et], 0, 0, 0);
        }
        __builtin_amdgcn_s_setprio(0);
      }
      __syncthreads();  // drains prefetch (vmcnt) + release buffers
    }
    // epilogue
    float inv[4];
    #pragma unroll
    for (int r = 0; r < 4; r++) inv[r] = 1.0f / lrun[r];
    #pragma unroll
    for (int et = 0; et < 32; et++)
      #pragma unroll
      for (int r = 0; r < 4; r++) {
        int q = q0w + lg * 4 + r;
        out[((size_t)(batch * LSEQ + q)) * DIM + et * 16 + l15] = oacc[et][r] * inv[r];
      }
  }
}

extern "C" void kernel_launch(void* const* d_in, const int* in_sizes, int n_in,
                              void* d_out, int out_size, void* d_ws, size_t ws_size,
                              hipStream_t stream) {
  const float* Ez = (const float*)d_in[0];
  const float* Wq = (const float*)d_in[1];
  const float* Wk = (const float*)d_in[2];
  const float* Wv = (const float*)d_in[3];
  const int* zp = (const int*)d_in[4];
  float* out = (float*)d_out;
  short* Qb = (short*)d_ws;
  short* Kb = Qb + (size_t)NB * LSEQ * DIM;
  short* Vtb = Kb + (size_t)NB * LSEQ * DIM;
  hipLaunchKernelGGL(proj_kernel, dim3(512, 1, 3), dim3(512), 0, stream,
                     Ez, Wq, Wk, Wv, zp, Qb, Kb, Vtb);
  hipLaunchKernelGGL(attn_kernel, dim3(8, 32), dim3(512), 0, stream,
                     Qb, Kb, Vtb, out);
}

// Round 5
// 661.043 us; speedup vs baseline: 2.4297x; 1.3057x over previous
//
#include <hip/hip_runtime.h>
#include <hip/hip_bf16.h>

// SelfAttention: out = softmax(causal((Ez Wq^T)(Ez Wk^T)^T / sqrt(512))) (Ez Wv^T)
// B=32, L=2048, DIM=512. f32 in/out; bf16 MFMA internally.
// ws: Qb (bf16, Q*SCALE pre-folded), Kb (bf16), Vtb (bf16, transposed [b][e][l]).
// Wb (bf16 W[z] for q,k,v) lives in d_out scratch (proj finishes before attn writes out).

typedef __attribute__((ext_vector_type(8))) short short8;
typedef __attribute__((ext_vector_type(4))) short short4v;
typedef __attribute__((ext_vector_type(4))) float f32x4;

#define DIM 512
#define LSEQ 2048
#define NB 32
#define SCALE 0.04419417382415922f       // 1/sqrt(512), folded into Qb at proj
#define LOG2E 1.4426950408889634f        // scores -> exp2 domain

__device__ __forceinline__ short f2bs(float f) {
  __hip_bfloat16 h = __float2bfloat16(f);
  return __builtin_bit_cast(short, h);
}

__device__ __forceinline__ void gld16(const void* g, void* l) {
  __builtin_amdgcn_global_load_lds(
      (const unsigned int __attribute__((address_space(1)))*)g,
      (unsigned int __attribute__((address_space(3)))*)l, 16, 0, 0);
}

// ---------------- W[z] f32 -> bf16 once: Wb[g][n][d] ----------------
__global__ __launch_bounds__(256) void wcvt_kernel(
    const float* __restrict__ Wq, const float* __restrict__ Wk,
    const float* __restrict__ Wv, const int* __restrict__ zp,
    short* __restrict__ Wb) {
  int z = *zp;
  int i = blockIdx.x * 256 + threadIdx.x;      // 98304 threads x 8 elems
  int g = i >> 15;                             // 32768 chunks per matrix
  int off = (i & 32767) * 8;
  const float* src = (g == 0 ? Wq : (g == 1 ? Wk : Wv)) + (size_t)z * DIM * DIM + off;
  float4 a = *(const float4*)src, b = *(const float4*)(src + 4);
  short8 v;
  v[0]=f2bs(a.x); v[1]=f2bs(a.y); v[2]=f2bs(a.z); v[3]=f2bs(a.w);
  v[4]=f2bs(b.x); v[5]=f2bs(b.y); v[6]=f2bs(b.z); v[7]=f2bs(b.w);
  *(short8*)&Wb[(size_t)g * DIM * DIM + off] = v;
}

// ---------------- projection GEMM: C[m][n] = sum_d Ez[m][d] * Wb[g][n][d] ----
// BM=128, BN=512, BK=32, 8 waves (2m x 4n: 64x128 per wave). Double-buffered,
// B staged via global_load_lds (bf16), A staged f32->cvt->ds_write (8 KB/kt).
__global__ __launch_bounds__(512, 2) void proj_kernel(
    const float* __restrict__ Ez, const short* __restrict__ Wb,
    short* __restrict__ Qb, short* __restrict__ Kb, short* __restrict__ Vtb) {
  int g = blockIdx.z;
  const short* W = Wb + (size_t)g * DIM * DIM;
  __shared__ short As[2][128 * 32];  // 16 KB
  __shared__ short Bs[2][512 * 32];  // 64 KB
  int tid = threadIdx.x, lane = tid & 63, wid = tid >> 6;
  int l15 = lane & 15, lg = lane >> 4;
  int m0 = blockIdx.x * 128;
  int wr = wid >> 2, nw = wid & 3;   // wave tile: m in [wr*64, +64), n in [nw*128, +128)
  f32x4 zero4 = {0.f, 0.f, 0.f, 0.f};
  f32x4 acc[4][8];
  #pragma unroll
  for (int m = 0; m < 4; m++)
    #pragma unroll
    for (int n = 0; n < 8; n++) acc[m][n] = zero4;

  int arow = tid >> 2, acg = tid & 3;          // A stage: 128 rows x 4 col-groups
  int brow16 = lane >> 2, bcg = lane & 3;      // B stage: 16 rows/instr x 4 col-groups

  // prologue: stage kt=0
  {
    const float* asrc = Ez + (size_t)(m0 + arow) * DIM + acg * 8;
    float4 a0 = *(const float4*)asrc, a1 = *(const float4*)(asrc + 4);
    short8 av;
    av[0]=f2bs(a0.x); av[1]=f2bs(a0.y); av[2]=f2bs(a0.z); av[3]=f2bs(a0.w);
    av[4]=f2bs(a1.x); av[5]=f2bs(a1.y); av[6]=f2bs(a1.z); av[7]=f2bs(a1.w);
    *(short8*)&As[0][arow * 32 + acg * 8] = av;
    #pragma unroll
    for (int ii = 0; ii < 4; ii++) {
      int nb = wid * 64 + ii * 16;
      gld16(W + (size_t)(nb + brow16) * DIM + bcg * 8, &Bs[0][nb * 32]);
    }
  }
  __syncthreads();

  #pragma unroll 2
  for (int kt = 0; kt < 16; kt++) {
    int cur = kt & 1;
    float4 a0, a1;
    if (kt < 15) {  // issue next-tile loads early
      const float* asrc = Ez + (size_t)(m0 + arow) * DIM + (kt + 1) * 32 + acg * 8;
      a0 = *(const float4*)asrc;
      a1 = *(const float4*)(asrc + 4);
      #pragma unroll
      for (int ii = 0; ii < 4; ii++) {
        int nb = wid * 64 + ii * 16;
        gld16(W + (size_t)(nb + brow16) * DIM + (kt + 1) * 32 + bcg * 8, &Bs[cur ^ 1][nb * 32]);
      }
    }
    short8 af[4], bf[8];
    #pragma unroll
    for (int m = 0; m < 4; m++)
      af[m] = *(const short8*)&As[cur][(wr * 64 + m * 16 + l15) * 32 + lg * 8];
    #pragma unroll
    for (int n = 0; n < 8; n++)
      bf[n] = *(const short8*)&Bs[cur][(nw * 128 + n * 16 + l15) * 32 + lg * 8];
    __builtin_amdgcn_s_setprio(1);
    #pragma unroll
    for (int m = 0; m < 4; m++)
      #pragma unroll
      for (int n = 0; n < 8; n++)
        acc[m][n] = __builtin_amdgcn_mfma_f32_16x16x32_bf16(af[m], bf[n], acc[m][n], 0, 0, 0);
    __builtin_amdgcn_s_setprio(0);
    if (kt < 15) {
      short8 av;
      av[0]=f2bs(a0.x); av[1]=f2bs(a0.y); av[2]=f2bs(a0.z); av[3]=f2bs(a0.w);
      av[4]=f2bs(a1.x); av[5]=f2bs(a1.y); av[6]=f2bs(a1.z); av[7]=f2bs(a1.w);
      *(short8*)&As[cur ^ 1][arow * 32 + acg * 8] = av;
    }
    __syncthreads();  // drains gld16 (vmcnt) + orders buffer reuse
  }

  // epilogue: C/D layout row=(lane>>4)*4+reg, col=lane&15
  if (g == 2) {
    #pragma unroll
    for (int m = 0; m < 4; m++) {
      int gm0 = m0 + wr * 64 + m * 16 + lg * 4;
      int b = gm0 >> 11, l0 = gm0 & (LSEQ - 1);
      #pragma unroll
      for (int n = 0; n < 8; n++) {
        int gn = nw * 128 + n * 16 + l15;
        short4v v;
        v[0]=f2bs(acc[m][n][0]); v[1]=f2bs(acc[m][n][1]);
        v[2]=f2bs(acc[m][n][2]); v[3]=f2bs(acc[m][n][3]);
        *(short4v*)&Vtb[((size_t)b * DIM + gn) * LSEQ + l0] = v;  // V transposed
      }
    }
  } else {
    short* dst = (g == 0 ? Qb : Kb);
    float sc = (g == 0 ? SCALE : 1.0f);  // fold 1/sqrt(512) into Q
    #pragma unroll
    for (int m = 0; m < 4; m++) {
      int gm0 = m0 + wr * 64 + m * 16 + lg * 4;
      #pragma unroll
      for (int n = 0; n < 8; n++) {
        int gn = nw * 128 + n * 16 + l15;
        #pragma unroll
        for (int r = 0; r < 4; r++)
          dst[(size_t)(gm0 + r) * DIM + gn] = f2bs(acc[m][n][r] * sc);
      }
    }
  }
}

// ---------------- flash attention (causal) ----------------
// 512 threads, 8 waves x 16 q-rows = 128-row Q tile; two tiles (i, 15-i) per
// block -> uniform 72 KV-tiles. KVBLK=32, K+V double-buffered, staged via
// global_load_lds (linear LDS dest, pre-swizzled GLOBAL source), 1 barrier/tile.
// Softmax: joint per-wave max (6 shfl), denom via ones-MFMA (no sum shuffles).
__device__ __forceinline__ void stage_kv(const short* __restrict__ Kb,
                                         const short* __restrict__ Vtb,
                                         short* Klbuf, short* Vlbuf,
                                         int batch, int t, int wid, int lane) {
  #pragma unroll
  for (int ii = 0; ii < 4; ii++) {          // K: rows wid, wid+8, wid+16, wid+24
    int r = wid + ii * 8;                   // r&7 == wid
    const short* src = Kb + (size_t)(batch * LSEQ + t * 32 + r) * DIM + ((lane ^ wid) * 8);
    gld16(src, Klbuf + r * 512);            // wave-uniform LDS base + lane*16
  }
  #pragma unroll
  for (int ii = 0; ii < 4; ii++) {          // V: 16 e-rows per instruction
    int e0 = (wid * 4 + ii) * 16;
    int e = e0 + (lane >> 2);
    int c = lane & 3;
    const short* src = Vtb + ((size_t)(batch * DIM + e)) * LSEQ + t * 32 + (((c ^ ((e >> 1) & 3))) * 8);
    gld16(src, Vlbuf + e0 * 32);
  }
}

__global__ __launch_bounds__(512, 2) void attn_kernel(
    const short* __restrict__ Qb, const short* __restrict__ Kb,
    const short* __restrict__ Vtb, float* __restrict__ out) {
  __shared__ short Kl[2][32 * 512];   // 64 KB dbuf
  __shared__ short Vl[2][512 * 32];   // 64 KB dbuf
  __shared__ short P_lds[8][16][36];  // per-wave P transpose, 9 KB
  int tid = threadIdx.x, lane = tid & 63, wid = tid >> 6;
  int l15 = lane & 15, lg = lane >> 4;
  int batch = blockIdx.y;
  int sw3 = (l15 >> 1) & 3;  // PV read swizzle (lane-const)
  f32x4 zero4 = {0.f, 0.f, 0.f, 0.f};
  short8 ones;               // bf16 1.0 splat for denominator MFMA
  #pragma unroll
  for (int i = 0; i < 8; i++) ones[i] = (short)0x3F80;

  for (int qpass = 0; qpass < 2; qpass++) {
    int qt = qpass ? 15 - (int)blockIdx.x : (int)blockIdx.x;
    int qb0 = qt * 128;
    int q0w = qb0 + wid * 16;
    int nt = qt * 4 + 4;

    stage_kv(Kb, Vtb, Kl[0], Vl[0], batch, 0, wid, lane);  // prologue prefetch

    short8 qf[16];  // Q rows in regs (pre-scaled by 1/sqrt(512) at proj)
    const short* qrow = Qb + (size_t)(batch * LSEQ + q0w + l15) * DIM;
    #pragma unroll
    for (int kt = 0; kt < 16; kt++) qf[kt] = *(const short8*)(qrow + kt * 32 + lg * 8);

    f32x4 oacc[32];
    #pragma unroll
    for (int i = 0; i < 32; i++) oacc[i] = zero4;
    f32x4 dacc = zero4;   // per-row softmax denominator (via ones-MFMA)
    float mrun = -1e30f;  // joint running max (uniform across wave)

    __syncthreads();  // drains prologue stage (vmcnt) + syncs

    for (int t = 0; t < nt; t++) {
      int cur = t & 1;
      if (t + 1 < nt)
        stage_kv(Kb, Vtb, Kl[cur ^ 1], Vl[cur ^ 1], batch, t + 1, wid, lane);  // prefetch

      if (t * 32 <= q0w + 15) {  // wave-local causal skip
        const short* Kc = Kl[cur];
        const short* Vc = Vl[cur];
        f32x4 sacc[2] = {zero4, zero4};
        __builtin_amdgcn_s_setprio(1);
        #pragma unroll
        for (int kt = 0; kt < 16; kt++) {
          #pragma unroll
          for (int c = 0; c < 2; c++) {
            int kr = c * 16 + l15;
            int j = kt * 4 + lg;
            short8 bk = *(const short8*)&Kc[kr * 512 + ((j ^ (kr & 7)) * 8)];
            sacc[c] = __builtin_amdgcn_mfma_f32_16x16x32_bf16(qf[kt], bk, sacc[c], 0, 0, 0);
          }
        }
        __builtin_amdgcn_s_setprio(0);
        // masks + joint tile max (one 64-lane reduce; any per-row-consistent
        // subtraction constant is mathematically exact for softmax)
        float s0[4], s1[4];
        float mx = -1e30f;
        #pragma unroll
        for (int r = 0; r < 4; r++) {
          int q = q0w + lg * 4 + r;
          s0[r] = sacc[0][r] * LOG2E;
          s1[r] = sacc[1][r] * LOG2E;
          if (t * 32 + l15 > q) s0[r] = -1e30f;
          if (t * 32 + 16 + l15 > q) s1[r] = -1e30f;
          mx = fmaxf(mx, fmaxf(s0[r], s1[r]));
        }
        #pragma unroll
        for (int off = 1; off < 64; off <<= 1) mx = fmaxf(mx, __shfl_xor(mx, off, 64));
        if (mx > mrun + 11.5f) {  // defer-max; wave-uniform branch
          float alpha = exp2f(mrun - mx);
          mrun = mx;
          dacc[0] *= alpha; dacc[1] *= alpha; dacc[2] *= alpha; dacc[3] *= alpha;
          #pragma unroll
          for (int et = 0; et < 32; et++) {
            oacc[et][0] *= alpha; oacc[et][1] *= alpha;
            oacc[et][2] *= alpha; oacc[et][3] *= alpha;
          }
        }
        #pragma unroll
        for (int r = 0; r < 4; r++) {
          P_lds[wid][lg * 4 + r][l15] = f2bs(exp2f(s0[r] - mrun));
          P_lds[wid][lg * 4 + r][16 + l15] = f2bs(exp2f(s1[r] - mrun));
        }
        short8 pa = *(const short8*)&P_lds[wid][l15][lg * 8];  // wave-local RAW
        __builtin_amdgcn_s_setprio(1);
        dacc = __builtin_amdgcn_mfma_f32_16x16x32_bf16(pa, ones, dacc, 0, 0, 0);
        #pragma unroll
        for (int et = 0; et < 32; et++) {
          short8 bv = *(const short8*)&Vc[(et * 16 + l15) * 32 + ((lg ^ sw3) * 8)];
          oacc[et] = __builtin_amdgcn_mfma_f32_16x16x32_bf16(pa, bv, oacc[et], 0, 0, 0);
        }
        __builtin_amdgcn_s_setprio(0);
      }
      __syncthreads();  // drains prefetch (vmcnt) + release buffers
    }
    // epilogue: divide by denominator (row r lives at acc idx r, col l15)
    float inv[4];
    #pragma unroll
    for (int r = 0; r < 4; r++) inv[r] = 1.0f / dacc[r];
    #pragma unroll
    for (int et = 0; et < 32; et++)
      #pragma unroll
      for (int r = 0; r < 4; r++) {
        int q = q0w + lg * 4 + r;
        out[((size_t)(batch * LSEQ + q)) * DIM + et * 16 + l15] = oacc[et][r] * inv[r];
      }
  }
}

extern "C" void kernel_launch(void* const* d_in, const int* in_sizes, int n_in,
                              void* d_out, int out_size, void* d_ws, size_t ws_size,
                              hipStream_t stream) {
  const float* Ez = (const float*)d_in[0];
  const float* Wq = (const float*)d_in[1];
  const float* Wk = (const float*)d_in[2];
  const float* Wv = (const float*)d_in[3];
  const int* zp = (const int*)d_in[4];
  float* out = (float*)d_out;
  short* Qb = (short*)d_ws;
  short* Kb = Qb + (size_t)NB * LSEQ * DIM;
  short* Vtb = Kb + (size_t)NB * LSEQ * DIM;
  short* Wb = (short*)d_out;  // scratch: proj completes before attn writes out
  hipLaunchKernelGGL(wcvt_kernel, dim3(384), dim3(256), 0, stream,
                     Wq, Wk, Wv, zp, Wb);
  hipLaunchKernelGGL(proj_kernel, dim3(512, 1, 3), dim3(512), 0, stream,
                     Ez, Wb, Qb, Kb, Vtb);
  hipLaunchKernelGGL(attn_kernel, dim3(8, 32), dim3(512), 0, stream,
                     Qb, Kb, Vtb, out);
}

// Round 6
// 476.841 us; speedup vs baseline: 3.3682x; 1.3863x over previous
//
#include <hip/hip_runtime.h>
#include <hip/hip_bf16.h>

// SelfAttention: out = softmax(causal((Ez Wq^T)(Ez Wk^T)^T / sqrt(512))) (Ez Wv^T)
// B=32, L=2048, DIM=512. f32 in/out; bf16 MFMA internally.
// ws: Qb (bf16, Q*SCALE), Kb (bf16), Vtb (bf16, [b][t][e][32] tile-contiguous,
// chunk-XOR swizzle pre-baked). Wb (bf16 [g][kt][n][32], swizzled) in d_out scratch.

typedef __attribute__((ext_vector_type(8))) short short8;
typedef __attribute__((ext_vector_type(4))) short short4v;
typedef __attribute__((ext_vector_type(4))) float f32x4;

#define DIM 512
#define LSEQ 2048
#define NB 32
#define SCALE 0.04419417382415922f       // 1/sqrt(512), folded into Qb at proj
#define LOG2E 1.4426950408889634f        // scores -> exp2 domain

__device__ __forceinline__ short f2bs(float f) {
  __hip_bfloat16 h = __float2bfloat16(f);
  return __builtin_bit_cast(short, h);
}

__device__ __forceinline__ void gld16(const void* g, void* l) {
  __builtin_amdgcn_global_load_lds(
      (const unsigned int __attribute__((address_space(1)))*)g,
      (unsigned int __attribute__((address_space(3)))*)l, 16, 0, 0);
}

// ---- W[z] f32 -> bf16, layout [g][kt][n][32 d-chunk-swizzled] --------------
__global__ __launch_bounds__(256) void wcvt_kernel(
    const float* __restrict__ Wq, const float* __restrict__ Wk,
    const float* __restrict__ Wv, const int* __restrict__ zp,
    short* __restrict__ Wb) {
  int z = *zp;
  int i = blockIdx.x * 256 + threadIdx.x;      // 98304 threads x 8 elems
  int g = i >> 15;
  int off = (i & 32767) * 8;                   // flat [n][d], d fast
  int n = off >> 9, d0 = off & 511;
  int kt = d0 >> 5, c = d0 & 31;
  int sw = ((c >> 3) ^ ((n >> 1) & 3));
  const float* src = (g == 0 ? Wq : (g == 1 ? Wk : Wv)) + (size_t)z * DIM * DIM + off;
  float4 a = *(const float4*)src, b = *(const float4*)(src + 4);
  short8 v;
  v[0]=f2bs(a.x); v[1]=f2bs(a.y); v[2]=f2bs(a.z); v[3]=f2bs(a.w);
  v[4]=f2bs(b.x); v[5]=f2bs(b.y); v[6]=f2bs(b.z); v[7]=f2bs(b.w);
  *(short8*)&Wb[((size_t)(g * 16 + kt) * 512 + n) * 32 + sw * 8] = v;
}

// ---- projection GEMM: C[m][n] = sum_d Ez[m][d] * W[n][d] -------------------
// BM=64, BN=512, BK=32, 8 waves of 64x64 tiles (acc 4x4 -> VGPR<=128 ->
// 2 blocks/CU = 16 waves). B via linear gld16 from kt-contiguous Wb; A staged
// f32->cvt->swizzled ds_write. Double-buffered, 1 barrier/kt.
__global__ __launch_bounds__(512, 4) void proj_kernel(
    const float* __restrict__ Ez, const short* __restrict__ Wb,
    short* __restrict__ Qb, short* __restrict__ Kb, short* __restrict__ Vtb) {
  int g = blockIdx.z;
  const short* W = Wb + (size_t)g * 16 * 512 * 32;   // [kt][slab][512]
  __shared__ short As[2][64 * 32];    // 8 KB total
  __shared__ short Bs[2][512 * 32];   // 64 KB total
  int tid = threadIdx.x, lane = tid & 63, wid = tid >> 6;
  int l15 = lane & 15, lg = lane >> 4;
  int m0 = blockIdx.x * 64;
  int sw = (l15 >> 1) & 3;
  f32x4 zero4 = {0.f, 0.f, 0.f, 0.f};
  f32x4 acc[4][4];
  #pragma unroll
  for (int mi = 0; mi < 4; mi++)
    #pragma unroll
    for (int ni = 0; ni < 4; ni++) acc[mi][ni] = zero4;

  int arow = tid >> 3, aq = tid & 7;            // A: 64 rows x 8 f32x4 groups
  int aoff = arow * 32 + (((aq >> 1) ^ ((arow >> 1) & 3)) << 3) + (aq & 1) * 4;
  const float* aptr = Ez + (size_t)(m0 + arow) * DIM + aq * 4;

  {  // prologue: stage kt=0
    float4 a = *(const float4*)aptr;
    short4v av;
    av[0]=f2bs(a.x); av[1]=f2bs(a.y); av[2]=f2bs(a.z); av[3]=f2bs(a.w);
    *(short4v*)&As[0][aoff] = av;
    #pragma unroll
    for (int ii = 0; ii < 4; ii++) {
      int s = wid * 4 + ii;
      gld16(W + s * 512 + lane * 8, &Bs[0][s * 512]);
    }
  }
  __syncthreads();

  #pragma unroll 2
  for (int kt = 0; kt < 16; kt++) {
    int cur = kt & 1;
    float4 a;
    if (kt < 15) {  // issue next-tile loads early
      a = *(const float4*)(aptr + (kt + 1) * 32);
      #pragma unroll
      for (int ii = 0; ii < 4; ii++) {
        int s = wid * 4 + ii;
        gld16(W + (size_t)(kt + 1) * 16384 + s * 512 + lane * 8, &Bs[cur ^ 1][s * 512]);
      }
    }
    short8 af[4], bf[4];
    #pragma unroll
    for (int mi = 0; mi < 4; mi++)
      af[mi] = *(const short8*)&As[cur][(mi * 16 + l15) * 32 + ((lg ^ sw) << 3)];
    #pragma unroll
    for (int ni = 0; ni < 4; ni++)
      bf[ni] = *(const short8*)&Bs[cur][(wid * 64 + ni * 16 + l15) * 32 + ((lg ^ sw) << 3)];
    __builtin_amdgcn_s_setprio(1);
    #pragma unroll
    for (int mi = 0; mi < 4; mi++)
      #pragma unroll
      for (int ni = 0; ni < 4; ni++)
        acc[mi][ni] = __builtin_amdgcn_mfma_f32_16x16x32_bf16(af[mi], bf[ni], acc[mi][ni], 0, 0, 0);
    __builtin_amdgcn_s_setprio(0);
    if (kt < 15) {
      short4v av;
      av[0]=f2bs(a.x); av[1]=f2bs(a.y); av[2]=f2bs(a.z); av[3]=f2bs(a.w);
      *(short4v*)&As[cur ^ 1][aoff] = av;
    }
    __syncthreads();  // drains gld16 (vmcnt) + A writes (lgkm), orders reuse
  }

  // epilogue: C/D layout row=(lane>>4)*4+reg, col=lane&15
  if (g == 2) {
    #pragma unroll
    for (int mi = 0; mi < 4; mi++) {
      int gm0 = m0 + mi * 16 + lg * 4;
      int b = gm0 >> 11, l0 = gm0 & (LSEQ - 1);
      int t = l0 >> 5, c0 = l0 & 31;
      #pragma unroll
      for (int ni = 0; ni < 4; ni++) {
        int e = wid * 64 + ni * 16 + l15;
        short4v v;
        v[0]=f2bs(acc[mi][ni][0]); v[1]=f2bs(acc[mi][ni][1]);
        v[2]=f2bs(acc[mi][ni][2]); v[3]=f2bs(acc[mi][ni][3]);
        size_t idx = ((size_t)(b * 64 + t) * 512 + e) * 32
                     + (((c0 >> 3) ^ ((e >> 1) & 3)) << 3) + (c0 & 7);
        *(short4v*)&Vtb[idx] = v;   // tile-contiguous V, swizzle pre-baked
      }
    }
  } else {
    short* dst = (g == 0 ? Qb : Kb);
    float sc = (g == 0 ? SCALE : 1.0f);  // fold 1/sqrt(512) into Q
    #pragma unroll
    for (int mi = 0; mi < 4; mi++) {
      int gm0 = m0 + mi * 16 + lg * 4;
      #pragma unroll
      for (int ni = 0; ni < 4; ni++) {
        int gn = wid * 64 + ni * 16 + l15;
        #pragma unroll
        for (int r = 0; r < 4; r++)
          dst[(size_t)(gm0 + r) * DIM + gn] = f2bs(acc[mi][ni][r] * sc);
      }
    }
  }
}

// ---- flash attention (causal) ----------------------------------------------
// 512 threads, 8 waves x 16 q-rows = 128-row Q tile; two tiles (15-y then y)
// per block -> uniform 68 KV-tiles, long pass first (L2 temporal alignment).
// Grid x=batch -> all 8 blocks of a batch share an XCD. KVBLK=32, K+V dbuf,
// staged via linear global_load_lds (V tile-contiguous), 1 barrier/tile.
__device__ __forceinline__ void stage_kv(const short* __restrict__ Kb,
                                         const short* __restrict__ Vtb,
                                         short* Klbuf, short* Vlbuf,
                                         int batch, int t, int wid, int lane) {
  #pragma unroll
  for (int ii = 0; ii < 4; ii++) {          // K: rows wid, wid+8, wid+16, wid+24
    int r = wid + ii * 8;                   // r&7 == wid
    const short* src = Kb + (size_t)(batch * LSEQ + t * 32 + r) * DIM + ((lane ^ wid) * 8);
    gld16(src, Klbuf + r * 512);            // wave-uniform LDS base + lane*16
  }
  const short* vt = Vtb + (size_t)(batch * 64 + t) * (512 * 32);  // contiguous 32KB
  #pragma unroll
  for (int ii = 0; ii < 4; ii++) {
    int s = wid * 4 + ii;
    gld16(vt + s * 512 + lane * 8, Vlbuf + s * 512);
  }
}

__global__ __launch_bounds__(512, 2) void attn_kernel(
    const short* __restrict__ Qb, const short* __restrict__ Kb,
    const short* __restrict__ Vtb, float* __restrict__ out) {
  __shared__ short Kl[2][32 * 512];   // 64 KB dbuf
  __shared__ short Vl[2][512 * 32];   // 64 KB dbuf
  __shared__ short P_lds[8][16][36];  // per-wave P transpose, 9 KB
  int tid = threadIdx.x, lane = tid & 63, wid = tid >> 6;
  int l15 = lane & 15, lg = lane >> 4;
  int batch = blockIdx.x;
  int sw3 = (l15 >> 1) & 3;  // PV read swizzle (lane-const)
  f32x4 zero4 = {0.f, 0.f, 0.f, 0.f};
  short8 ones;               // bf16 1.0 splat for denominator MFMA
  #pragma unroll
  for (int i = 0; i < 8; i++) ones[i] = (short)0x3F80;

  for (int qpass = 0; qpass < 2; qpass++) {
    int qt = qpass ? (int)blockIdx.y : 15 - (int)blockIdx.y;  // long pass first
    int qb0 = qt * 128;
    int q0w = qb0 + wid * 16;
    int nt = qt * 4 + 4;

    stage_kv(Kb, Vtb, Kl[0], Vl[0], batch, 0, wid, lane);  // prologue prefetch

    short8 qf[16];  // Q rows in regs (pre-scaled by 1/sqrt(512) at proj)
    const short* qrow = Qb + (size_t)(batch * LSEQ + q0w + l15) * DIM;
    #pragma unroll
    for (int kt = 0; kt < 16; kt++) qf[kt] = *(const short8*)(qrow + kt * 32 + lg * 8);

    f32x4 oacc[32];
    #pragma unroll
    for (int i = 0; i < 32; i++) oacc[i] = zero4;
    f32x4 dacc = zero4;   // per-row softmax denominator (via ones-MFMA)
    float mrun = -1e30f;  // joint running max (uniform across wave)

    __syncthreads();  // drains prologue stage (vmcnt) + syncs

    for (int t = 0; t < nt; t++) {
      int cur = t & 1;
      if (t + 1 < nt)
        stage_kv(Kb, Vtb, Kl[cur ^ 1], Vl[cur ^ 1], batch, t + 1, wid, lane);  // prefetch

      if (t * 32 <= q0w + 15) {  // wave-local causal skip
        const short* Kc = Kl[cur];
        const short* Vc = Vl[cur];
        f32x4 sacc[2] = {zero4, zero4};
        __builtin_amdgcn_s_setprio(1);
        #pragma unroll
        for (int kt = 0; kt < 16; kt++) {
          #pragma unroll
          for (int c = 0; c < 2; c++) {
            int kr = c * 16 + l15;
            int j = kt * 4 + lg;
            short8 bk = *(const short8*)&Kc[kr * 512 + ((j ^ (kr & 7)) * 8)];
            sacc[c] = __builtin_amdgcn_mfma_f32_16x16x32_bf16(qf[kt], bk, sacc[c], 0, 0, 0);
          }
        }
        __builtin_amdgcn_s_setprio(0);
        // masks + joint tile max (one 64-lane reduce; per-row-consistent
        // subtraction constant is exact for softmax)
        float s0[4], s1[4];
        float mx = -1e30f;
        #pragma unroll
        for (int r = 0; r < 4; r++) {
          int q = q0w + lg * 4 + r;
          s0[r] = sacc[0][r] * LOG2E;
          s1[r] = sacc[1][r] * LOG2E;
          if (t * 32 + l15 > q) s0[r] = -1e30f;
          if (t * 32 + 16 + l15 > q) s1[r] = -1e30f;
          mx = fmaxf(mx, fmaxf(s0[r], s1[r]));
        }
        #pragma unroll
        for (int off = 1; off < 64; off <<= 1) mx = fmaxf(mx, __shfl_xor(mx, off, 64));
        if (mx > mrun + 11.5f) {  // defer-max; wave-uniform branch
          float alpha = exp2f(mrun - mx);
          mrun = mx;
          dacc[0] *= alpha; dacc[1] *= alpha; dacc[2] *= alpha; dacc[3] *= alpha;
          #pragma unroll
          for (int et = 0; et < 32; et++) {
            oacc[et][0] *= alpha; oacc[et][1] *= alpha;
            oacc[et][2] *= alpha; oacc[et][3] *= alpha;
          }
        }
        #pragma unroll
        for (int r = 0; r < 4; r++) {
          P_lds[wid][lg * 4 + r][l15] = f2bs(exp2f(s0[r] - mrun));
          P_lds[wid][lg * 4 + r][16 + l15] = f2bs(exp2f(s1[r] - mrun));
        }
        short8 pa = *(const short8*)&P_lds[wid][l15][lg * 8];  // wave-local RAW
        __builtin_amdgcn_s_setprio(1);
        dacc = __builtin_amdgcn_mfma_f32_16x16x32_bf16(pa, ones, dacc, 0, 0, 0);
        #pragma unroll
        for (int et = 0; et < 32; et++) {
          short8 bv = *(const short8*)&Vc[(et * 16 + l15) * 32 + ((lg ^ sw3) * 8)];
          oacc[et] = __builtin_amdgcn_mfma_f32_16x16x32_bf16(pa, bv, oacc[et], 0, 0, 0);
        }
        __builtin_amdgcn_s_setprio(0);
      }
      __syncthreads();  // drains prefetch (vmcnt) + release buffers
    }
    // epilogue: divide by denominator
    float inv[4];
    #pragma unroll
    for (int r = 0; r < 4; r++) inv[r] = 1.0f / dacc[r];
    #pragma unroll
    for (int et = 0; et < 32; et++)
      #pragma unroll
      for (int r = 0; r < 4; r++) {
        int q = q0w + lg * 4 + r;
        out[((size_t)(batch * LSEQ + q)) * DIM + et * 16 + l15] = oacc[et][r] * inv[r];
      }
  }
}

extern "C" void kernel_launch(void* const* d_in, const int* in_sizes, int n_in,
                              void* d_out, int out_size, void* d_ws, size_t ws_size,
                              hipStream_t stream) {
  const float* Ez = (const float*)d_in[0];
  const float* Wq = (const float*)d_in[1];
  const float* Wk = (const float*)d_in[2];
  const float* Wv = (const float*)d_in[3];
  const int* zp = (const int*)d_in[4];
  float* out = (float*)d_out;
  short* Qb = (short*)d_ws;
  short* Kb = Qb + (size_t)NB * LSEQ * DIM;
  short* Vtb = Kb + (size_t)NB * LSEQ * DIM;
  short* Wb = (short*)d_out;  // scratch: proj completes before attn writes out
  hipLaunchKernelGGL(wcvt_kernel, dim3(384), dim3(256), 0, stream,
                     Wq, Wk, Wv, zp, Wb);
  hipLaunchKernelGGL(proj_kernel, dim3(1024, 1, 3), dim3(512), 0, stream,
                     Ez, Wb, Qb, Kb, Vtb);
  hipLaunchKernelGGL(attn_kernel, dim3(32, 8), dim3(512), 0, stream,
                     Qb, Kb, Vtb, out);
}